// Round 8
// baseline (948.255 us; speedup 1.0000x reference)
//
#include <hip/hip_runtime.h>
#include <hip/hip_bf16.h>
#include <math.h>

// ComplexTransformerBlock: B=4 S=1024 L=256 F=512 CD=768 NH=8 (d=64) E=8 HID=2048
// Round 8: cattn 64-key tiles (halved softmax/barrier overhead; P aliases into sK
// after 3rd barrier); sao/caq/cao moved to 128x128 tile (RESID added to cgemm128).

#define NTOK 4096
#define FF   512
#define CDIM 768
#define NEXP 8
#define HID  2048
#define TMAX128 40
#define NPAD128 (TMAX128 * 128)   // 5120

typedef __hip_bfloat16 bf16;
typedef short bf16x8 __attribute__((ext_vector_type(8)));
typedef float f32x4  __attribute__((ext_vector_type(4)));

struct Ptr6 { const float* p[6]; };
struct WPackAll {
    const float* sR[8]; const float* sI[8];
    bf16* dR[8]; bf16* dI[8];
    int kdiv[8];
};

__device__ __forceinline__ short f2bf(float x) {          // raw bf16 bits (for short* bufs)
    unsigned u = __float_as_uint(x);
    unsigned r = (u + 0x7fff + ((u >> 16) & 1)) >> 16;
    return (short)r;
}
__device__ __forceinline__ float bf2f(short s) {
    return __uint_as_float(((unsigned)(unsigned short)s) << 16);
}
__device__ __forceinline__ void gload16(const void* g, void* l) {
    __builtin_amdgcn_global_load_lds(
        (const __attribute__((address_space(1))) unsigned int*)g,
        (__attribute__((address_space(3))) unsigned int*)l, 16, 0, 0);
}

// --------------------------- fused complex LN -> A1 [Ah|Al] (M x 1024 bf16)
__global__ __launch_bounds__(256)
void cln_expand(const float* __restrict__ xr, const float* __restrict__ xi,
                const float* __restrict__ g,
                bf16* __restrict__ dR, bf16* __restrict__ dI)
{
    long base = (long)blockIdx.x * FF;
    int t = threadIdx.x;
    int j0 = t, j1 = t + 256;
    float xr0 = xr[base + j0], xi0 = xi[base + j0];
    float xr1 = xr[base + j1], xi1 = xi[base + j1];
    float a0 = sqrtf(xr0 * xr0 + xi0 * xi0 + 1e-6f);
    float a1 = sqrtf(xr1 * xr1 + xi1 * xi1 + 1e-6f);
    float s = a0 + a1;
#pragma unroll
    for (int off = 32; off >= 1; off >>= 1) s += __shfl_xor(s, off);
    __shared__ float wsum[4];
    if ((t & 63) == 0) wsum[t >> 6] = s;
    __syncthreads();
    float mean = (wsum[0] + wsum[1] + wsum[2] + wsum[3]) * (1.0f / 512.0f);
    float d0 = g[j0] * (a0 / (mean + 1e-6f)) / (a0 + 1e-6f);
    float d1 = g[j1] * (a1 / (mean + 1e-6f)) / (a1 + 1e-6f);
    long d = (long)blockIdx.x * 1024;
    float h; bf16 hh;
    h = xr0 * d0; hh = __float2bfloat16(h);
    dR[d + j0] = hh; dR[d + 512 + j0] = __float2bfloat16(h - __bfloat162float(hh));
    h = xi0 * d0; hh = __float2bfloat16(h);
    dI[d + j0] = hh; dI[d + 512 + j0] = __float2bfloat16(h - __bfloat162float(hh));
    h = xr1 * d1; hh = __float2bfloat16(h);
    dR[d + j1] = hh; dR[d + 512 + j1] = __float2bfloat16(h - __bfloat162float(hh));
    h = xi1 * d1; hh = __float2bfloat16(h);
    dI[d + j1] = hh; dI[d + 512 + j1] = __float2bfloat16(h - __bfloat162float(hh));
}

// --------------------- fused complex LN -> h3 (bf16) + phase routing (eidx)
__global__ __launch_bounds__(256)
void cln_route(const float* __restrict__ xr, const float* __restrict__ xi,
               const float* __restrict__ g,
               bf16* __restrict__ h3r, bf16* __restrict__ h3i,
               int* __restrict__ eidx)
{
    long base = (long)blockIdx.x * FF;
    int t = threadIdx.x;
    int j0 = t, j1 = t + 256;
    float xr0 = xr[base + j0], xi0 = xi[base + j0];
    float xr1 = xr[base + j1], xi1 = xi[base + j1];
    float a0 = sqrtf(xr0 * xr0 + xi0 * xi0 + 1e-6f);
    float a1 = sqrtf(xr1 * xr1 + xi1 * xi1 + 1e-6f);
    float s = a0 + a1;
#pragma unroll
    for (int off = 32; off >= 1; off >>= 1) s += __shfl_xor(s, off);
    __shared__ float wsum[4];
    __shared__ double wss[4], wcc[4];
    if ((t & 63) == 0) wsum[t >> 6] = s;
    __syncthreads();
    float mean = (wsum[0] + wsum[1] + wsum[2] + wsum[3]) * (1.0f / 512.0f);
    float d0 = g[j0] * (a0 / (mean + 1e-6f)) / (a0 + 1e-6f);
    float d1 = g[j1] * (a1 / (mean + 1e-6f)) / (a1 + 1e-6f);
    float h0r = xr0 * d0, h0i = xi0 * d0;
    float h1r = xr1 * d1, h1i = xi1 * d1;
    h3r[base + j0] = __float2bfloat16(h0r);
    h3i[base + j0] = __float2bfloat16(h0i);
    h3r[base + j1] = __float2bfloat16(h1r);
    h3i[base + j1] = __float2bfloat16(h1i);
    float ph0 = atan2f(h0i, h0r), ph1 = atan2f(h1i, h1r);
    double ss = (double)sinf(ph0) + (double)sinf(ph1);
    double cc = (double)cosf(ph0) + (double)cosf(ph1);
#pragma unroll
    for (int off = 32; off >= 1; off >>= 1) {
        ss += __shfl_xor(ss, off);
        cc += __shfl_xor(cc, off);
    }
    if ((t & 63) == 0) { wss[t >> 6] = ss; wcc[t >> 6] = cc; }
    __syncthreads();
    if (t == 0) {
        float msin = (float)((wss[0] + wss[1] + wss[2] + wss[3]) * (1.0 / 512.0));
        float mcos = (float)((wcc[0] + wcc[1] + wcc[2] + wcc[3]) * (1.0 / 512.0));
        float tp = atan2f(msin, mcos);
        float a = (tp + 3.14159274101257324f) / 6.28318548202514648f * 8.0f;
        int k = (int)floorf(a);
        k = min(max(k, 0), NEXP - 1);
        eidx[blockIdx.x] = k;
    }
}

// ------------------------------------------------- fp32 -> [Ah|Al] (ctx only)
__global__ __launch_bounds__(256)
void expandA_x2(const float* __restrict__ sR, const float* __restrict__ sI,
                bf16* __restrict__ dR, bf16* __restrict__ dI, int K)
{
    int k = blockIdx.x * 256 + threadIdx.x;
    int m = blockIdx.y;
    long s = (long)m * K + k;
    long d = (long)m * 2 * K + k;
    float a = sR[s];
    bf16 ah = __float2bfloat16(a);
    dR[d] = ah; dR[d + K] = __float2bfloat16(a - __bfloat162float(ah));
    float b = sI[s];
    bf16 bh = __float2bfloat16(b);
    dI[d] = bh; dI[d + K] = __float2bfloat16(b - __bfloat162float(bh));
}

// --------------------------- all 8 attention W packs in one dispatch (x2 phys)
__global__ __launch_bounds__(256)
void expandW_all(WPackAll p)
{
    int z = blockIdx.z;
    int kdiv = p.kdiv[z];
    int kc = blockIdx.y;
    if (kc >= 2 * kdiv) return;
    const int N = FF;
    int g = blockIdx.x * 256 + threadIdx.x;
    int nt = g >> 6, l = g & 63;
    int lo = (kc >= kdiv);
    int kb = (kc - (lo ? kdiv : 0)) * 32 + (l >> 4) * 8;
    int n  = nt * 16 + (l & 15);
    long dbase = ((long)kc * (N >> 4) + nt) * 512 + l * 8;
    const float* sR = p.sR[z]; const float* sI = p.sI[z];
    bf16* dR = p.dR[z]; bf16* dI = p.dI[z];
#pragma unroll
    for (int j = 0; j < 8; j++) {
        float a = sR[(long)(kb + j) * N + n];
        bf16 ah = __float2bfloat16(a);
        dR[dbase + j] = lo ? __float2bfloat16(a - __bfloat162float(ah)) : ah;
        float b = sI[(long)(kb + j) * N + n];
        bf16 bh = __float2bfloat16(b);
        dI[dbase + j] = lo ? __float2bfloat16(b - __bfloat162float(bh)) : bh;
    }
}

// W -> packed plain bf16, expert-strided (MoE weights)
__global__ __launch_bounds__(256)
void convW_packed(const float* __restrict__ sR, const float* __restrict__ sI,
                  bf16* __restrict__ dR, bf16* __restrict__ dI,
                  int N, long estride)
{
    int g = blockIdx.x * 256 + threadIdx.x;
    int nt = g >> 6, l = g & 63;
    int kc = blockIdx.y;
    int e  = blockIdx.z;
    const float* srcR = sR + (long)e * estride;
    const float* srcI = sI + (long)e * estride;
    bf16* dstR = dR + (long)e * estride;
    bf16* dstI = dI + (long)e * estride;
    int kb = kc * 32 + (l >> 4) * 8;
    int n  = nt * 16 + (l & 15);
    long dbase = ((long)kc * (N >> 4) + nt) * 512 + l * 8;
#pragma unroll
    for (int j = 0; j < 8; j++) {
        dstR[dbase + j] = __float2bfloat16(srcR[(long)(kb + j) * N + n]);
        dstI[dbase + j] = __float2bfloat16(srcI[(long)(kb + j) * N + n]);
    }
}

// ---------------------------------------------- complex MFMA GEMM 128x128
// 4 waves in 2x2; each wave 64x64 quadrant. 64 KB LDS, BK=64. bandM>0: 1D grid,
// linear%8 (~XCD) selects a tile-row band of bandM rows.
template<bool X3, bool EXPERT, bool GATHER, bool MODRELU, bool RESID, bool OUTBF16>
__global__ __launch_bounds__(256, 2)
void cgemm128(const bf16* __restrict__ Ar, const bf16* __restrict__ Ai,
              int lda, int Kreal,
              const bf16* __restrict__ Wr0, const bf16* __restrict__ Wi0,
              long wz, long westride, int ntTot, int kdiv,
              Ptr6 bias, int bstride, const float* __restrict__ mb,
              const float* __restrict__ Rr, const float* __restrict__ Ri,
              void* __restrict__ Cr0, void* __restrict__ Ci0, long cz,
              int ldc, int Kp, int bandM,
              const int* __restrict__ order, const int* __restrict__ tileExpert)
{
    __shared__ short sA[16384];   // 32 KB: [(ri*2+kc)*8 + mt][lane64][8]
    __shared__ short sW[16384];   // 32 KB: [(ri*2+kc)*8 + nt][lane64][8]
    int tm, tn, z;
    if (bandM > 0) {
        int L = blockIdx.x;
        int xcd = L & 7, idx = L >> 3;
        tm = xcd * bandM + idx % bandM;
        tn = idx / bandM;
        z = 0;
    } else {
        tm = blockIdx.x; tn = blockIdx.y; z = blockIdx.z;
    }
    const bf16* Wr = Wr0 + (long)z * wz;
    const bf16* Wi = Wi0 + (long)z * wz;
    const float* br = bias.p[2 * z];
    const float* bi = bias.p[2 * z + 1];
    void* Crv = (char*)Cr0 + (long)z * cz;
    void* Civ = (char*)Ci0 + (long)z * cz;
    if (EXPERT) {
        int e = tileExpert[tm];
        if (e < 0) return;
        Wr += (long)e * westride;  Wi += (long)e * westride;
        br += (long)e * bstride;   bi += (long)e * bstride;
        if (MODRELU) mb += (long)e * bstride;
    }
    int t = threadIdx.x;
    int l = t & 63, w = t >> 6;
    int riS = w >> 1, kcS = w & 1;
    const bf16* Asrc = riS ? Ai : Ar;
    const bf16* Wsrc = riS ? Wi : Wr;
    int kq8 = (l >> 4) * 8;
    long arb[8];
#pragma unroll
    for (int mt = 0; mt < 8; mt++) {
        int grow = tm * 128 + mt * 16 + (l & 15);
        int tok = grow;
        if (GATHER) { int gg = order[grow]; tok = (gg < 0) ? 0 : gg; }
        arb[mt] = (long)tok * lda;
    }
    int wm = w & 1, wn = w >> 1;

    f32x4 zf = {0.f, 0.f, 0.f, 0.f};
    f32x4 accR[4][4], accI[4][4];
#pragma unroll
    for (int a = 0; a < 4; a++)
#pragma unroll
        for (int b = 0; b < 4; b++) { accR[a][b] = zf; accI[a][b] = zf; }

    const bf16x8 sgn = {(short)0x8000,(short)0x8000,(short)0x8000,(short)0x8000,
                        (short)0x8000,(short)0x8000,(short)0x8000,(short)0x8000};

    for (int k0 = 0; k0 < Kp; k0 += 64) {
        __syncthreads();
        int lc = k0 + kcS * 32;
        int acol = (X3 && lc >= 2 * Kreal) ? lc - 2 * Kreal : lc;
#pragma unroll
        for (int mt = 0; mt < 8; mt++)
            gload16(Asrc + arb[mt] + acol + kq8,
                    &sA[(((riS * 2 + kcS) * 8 + mt) << 9)]);
        int kcl = (k0 >> 5) + kcS;
        int pkc = (X3 && kcl >= kdiv) ? kcl - kdiv : kcl;
        const bf16* wb = Wsrc + (((long)pkc * ntTot + tn * 8) << 9) + l * 8;
#pragma unroll
        for (int ntl = 0; ntl < 8; ntl++)
            gload16(wb + (ntl << 9),
                    &sW[(((riS * 2 + kcS) * 8 + ntl) << 9)]);
        __syncthreads();
#pragma unroll
        for (int kc = 0; kc < 2; kc++) {
            bf16x8 wrf[4], wif[4];
#pragma unroll
            for (int sn = 0; sn < 4; sn++) {
                wrf[sn] = *(const bf16x8*)&sW[(((kc * 8) + wn * 4 + sn) << 9) + l * 8];
                wif[sn] = *(const bf16x8*)&sW[((((2 + kc) * 8) + wn * 4 + sn) << 9) + l * 8];
            }
#pragma unroll
            for (int sm = 0; sm < 4; sm++) {
                bf16x8 ar = *(const bf16x8*)&sA[(((kc * 8) + wm * 4 + sm) << 9) + l * 8];
                bf16x8 ai = *(const bf16x8*)&sA[((((2 + kc) * 8) + wm * 4 + sm) << 9) + l * 8];
                bf16x8 na = ai ^ sgn;
#pragma unroll
                for (int sn = 0; sn < 4; sn++) {
                    accR[sm][sn] = __builtin_amdgcn_mfma_f32_16x16x32_bf16(ar, wrf[sn], accR[sm][sn], 0, 0, 0);
                    accR[sm][sn] = __builtin_amdgcn_mfma_f32_16x16x32_bf16(na, wif[sn], accR[sm][sn], 0, 0, 0);
                    accI[sm][sn] = __builtin_amdgcn_mfma_f32_16x16x32_bf16(ar, wif[sn], accI[sm][sn], 0, 0, 0);
                    accI[sm][sn] = __builtin_amdgcn_mfma_f32_16x16x32_bf16(ai, wrf[sn], accI[sm][sn], 0, 0, 0);
                }
            }
        }
    }
#pragma unroll
    for (int sm = 0; sm < 4; sm++)
#pragma unroll
        for (int sn = 0; sn < 4; sn++) {
            int row0 = tm * 128 + wm * 64 + sm * 16 + (l >> 4) * 4;
            int col  = tn * 128 + wn * 64 + sn * 16 + (l & 15);
            float bre = br[col], bie = bi[col];
            float mbe = MODRELU ? mb[col] : 0.f;
#pragma unroll
            for (int v = 0; v < 4; v++) {
                int row = row0 + v;
                float vr = accR[sm][sn][v] + bre;
                float vi = accI[sm][sn][v] + bie;
                if (MODRELU) {
                    float amp = sqrtf(vr * vr + vi * vi + 1e-10f);
                    float sc = fmaxf(amp + mbe, 0.f) / (amp + 1e-10f);
                    vr *= sc; vi *= sc;
                }
                long cidx = (long)row * ldc + col;
                if (RESID) { vr += Rr[cidx]; vi += Ri[cidx]; }
                if (OUTBF16) {
                    ((bf16*)Crv)[cidx] = __float2bfloat16(vr);
                    ((bf16*)Civ)[cidx] = __float2bfloat16(vi);
                } else {
                    ((float*)Crv)[cidx] = vr;
                    ((float*)Civ)[cidx] = vi;
                }
            }
        }
}

// -------------------------------------------------- complex MFMA GEMM 64x64
template<bool X3, bool EXPERT, bool GATHER, bool MODRELU, bool RESID, bool OUTBF16>
__global__ __launch_bounds__(256)
void cgemm_mfma(const bf16* __restrict__ Ar, const bf16* __restrict__ Ai,
                int lda, int Kreal,
                const bf16* __restrict__ Wr0, const bf16* __restrict__ Wi0,
                long wz, long westride, int ntTot, int kdiv,
                Ptr6 bias, int bstride, const float* __restrict__ mb,
                const float* __restrict__ Rr, const float* __restrict__ Ri,
                void* __restrict__ Cr0, void* __restrict__ Ci0, long cz,
                int ldc, int Kp,
                const int* __restrict__ order, const int* __restrict__ tileExpert)
{
    __shared__ short sA[8192];
    __shared__ short sW[8192];
    int tm = blockIdx.x, tn = blockIdx.y, z = blockIdx.z;
    const bf16* Wr = Wr0 + (long)z * wz;
    const bf16* Wi = Wi0 + (long)z * wz;
    const float* br = bias.p[2 * z];
    const float* bi = bias.p[2 * z + 1];
    void* Crv = (char*)Cr0 + (long)z * cz;
    void* Civ = (char*)Ci0 + (long)z * cz;
    if (EXPERT) {
        int e = tileExpert[tm];
        if (e < 0) return;
        Wr += (long)e * westride;  Wi += (long)e * westride;
        br += (long)e * bstride;   bi += (long)e * bstride;
        if (MODRELU) mb += (long)e * bstride;
    }
    int t = threadIdx.x;
    int l = t & 63, jj = t >> 6;
    int riS = jj >> 1, kcS = jj & 1;
    const bf16* Asrc = riS ? Ai : Ar;
    const bf16* Wsrc = riS ? Wi : Wr;
    int kq8 = (l >> 4) * 8;
    long arb[4];
#pragma unroll
    for (int mt = 0; mt < 4; mt++) {
        int grow = tm * 64 + mt * 16 + (l & 15);
        int tok = grow;
        if (GATHER) { int gg = order[grow]; tok = (gg < 0) ? 0 : gg; }
        arb[mt] = (long)tok * lda;
    }
    int wm = jj & 1, wn = jj >> 1;

    f32x4 zf = {0.f, 0.f, 0.f, 0.f};
    f32x4 accR[2][2], accI[2][2];
#pragma unroll
    for (int a = 0; a < 2; a++)
#pragma unroll
        for (int b = 0; b < 2; b++) { accR[a][b] = zf; accI[a][b] = zf; }

    const bf16x8 sgn = {(short)0x8000,(short)0x8000,(short)0x8000,(short)0x8000,
                        (short)0x8000,(short)0x8000,(short)0x8000,(short)0x8000};

    for (int k0 = 0; k0 < Kp; k0 += 64) {
        __syncthreads();
        int lc = k0 + kcS * 32;
        int acol = (X3 && lc >= 2 * Kreal) ? lc - 2 * Kreal : lc;
#pragma unroll
        for (int mt = 0; mt < 4; mt++)
            gload16(Asrc + arb[mt] + acol + kq8,
                    &sA[(((riS * 2 + kcS) << 2) + mt) << 9]);
        int kcl = (k0 >> 5) + kcS;
        int pkc = (X3 && kcl >= kdiv) ? kcl - kdiv : kcl;
        const bf16* wbase = Wsrc + (((long)pkc * ntTot + tn * 4) << 9) + l * 8;
#pragma unroll
        for (int ntl = 0; ntl < 4; ntl++)
            gload16(wbase + (ntl << 9),
                    &sW[(((riS * 2 + kcS) << 2) + ntl) << 9]);
        __syncthreads();
#pragma unroll
        for (int kc = 0; kc < 2; kc++) {
            bf16x8 arf[2], aif[2], naf[2], wrf[2], wif[2];
#pragma unroll
            for (int s = 0; s < 2; s++) {
                arf[s] = *(const bf16x8*)&sA[(((kc << 2) + wm * 2 + s) << 9) + l * 8];
                aif[s] = *(const bf16x8*)&sA[((((2 + kc) << 2) + wm * 2 + s) << 9) + l * 8];
                naf[s] = aif[s] ^ sgn;
                wrf[s] = *(const bf16x8*)&sW[(((kc << 2) + wn * 2 + s) << 9) + l * 8];
                wif[s] = *(const bf16x8*)&sW[((((2 + kc) << 2) + wn * 2 + s) << 9) + l * 8];
            }
#pragma unroll
            for (int sm = 0; sm < 2; sm++)
#pragma unroll
                for (int sn = 0; sn < 2; sn++) {
                    accR[sm][sn] = __builtin_amdgcn_mfma_f32_16x16x32_bf16(arf[sm], wrf[sn], accR[sm][sn], 0, 0, 0);
                    accR[sm][sn] = __builtin_amdgcn_mfma_f32_16x16x32_bf16(naf[sm], wif[sn], accR[sm][sn], 0, 0, 0);
                    accI[sm][sn] = __builtin_amdgcn_mfma_f32_16x16x32_bf16(arf[sm], wif[sn], accI[sm][sn], 0, 0, 0);
                    accI[sm][sn] = __builtin_amdgcn_mfma_f32_16x16x32_bf16(aif[sm], wrf[sn], accI[sm][sn], 0, 0, 0);
                }
        }
    }
#pragma unroll
    for (int sm = 0; sm < 2; sm++)
#pragma unroll
        for (int sn = 0; sn < 2; sn++) {
            int row0 = tm * 64 + (wm * 2 + sm) * 16 + (l >> 4) * 4;
            int col  = tn * 64 + (wn * 2 + sn) * 16 + (l & 15);
            float bre = br[col], bie = bi[col];
            float mbe = MODRELU ? mb[col] : 0.f;
#pragma unroll
            for (int v = 0; v < 4; v++) {
                int row = row0 + v;
                float vr = accR[sm][sn][v] + bre;
                float vi = accI[sm][sn][v] + bie;
                if (MODRELU) {
                    float amp = sqrtf(vr * vr + vi * vi + 1e-10f);
                    float sc = fmaxf(amp + mbe, 0.f) / (amp + 1e-10f);
                    vr *= sc; vi *= sc;
                }
                long cidx = (long)row * ldc + col;
                if (RESID) { vr += Rr[cidx]; vi += Ri[cidx]; }
                if (OUTBF16) {
                    ((bf16*)Crv)[cidx] = __float2bfloat16(vr);
                    ((bf16*)Civ)[cidx] = __float2bfloat16(vi);
                } else {
                    ((float*)Crv)[cidx] = vr;
                    ((float*)Civ)[cidx] = vi;
                }
            }
        }
}

// ----------- pack K/V into 64-key attention LDS fragment image (bf16 hi/lo)
// Per (b,h,kt64): 16384 shorts each for K and V, mirroring cattn's sK/sV.
__global__ __launch_bounds__(256)
void pack_kv(const float* __restrict__ kr, const float* __restrict__ ki,
             const float* __restrict__ vr, const float* __restrict__ vi,
             short* __restrict__ pK, short* __restrict__ pV, int Sk)
{
    const int F = FF;
    int kt = blockIdx.x, h = blockIdx.y, b = blockIdx.z;
    int nkt = gridDim.x;
    long blkbase = ((long)((b * 8 + h) * nkt) + kt) * 16384;
    int t = threadIdx.x;
    // K: B-fragments for scores, [ri][hl][c][nt4][64][8]
#pragma unroll
    for (int it = 0; it < 4; it++) {
        int p4 = t + 256 * it;
        int sl = p4 & 63, gg = p4 >> 6;       // gg 0..15 -> (ri, c, nt)
        int nt = gg & 3, c = (gg >> 2) & 1, ri = gg >> 3;
        int sq = sl >> 4, sn = sl & 15;
        const float* src = ri ? ki : kr;
        long base = ((long)(b * Sk + kt * 64 + nt * 16 + sn)) * F + h * 64 + c * 32 + sq * 8;
        long outH = blkbase + ((((ri * 2 + 0) * 2 + c) * 4 + nt) * 64 + sl) * 8;
        long outL = blkbase + ((((ri * 2 + 1) * 2 + c) * 4 + nt) * 64 + sl) * 8;
#pragma unroll
        for (int j = 0; j < 8; j++) {
            float x = src[base + j];
            short xh = f2bf(x);
            pK[outH + j] = xh;
            pK[outL + j] = f2bf(x - bf2f(xh));
        }
    }
    // V: B-fragments for PV, [ri][hl][kc][nt4][64][8]
#pragma unroll
    for (int it = 0; it < 4; it++) {
        int p4 = t + 256 * it;
        int sl = p4 & 63, gg = p4 >> 6;       // gg 0..15 -> (ri, kc, nt)
        int nt = gg & 3, kc = (gg >> 2) & 1, ri = gg >> 3;
        int sq = sl >> 4, sn = sl & 15;
        const float* src = ri ? vi : vr;
        long base = ((long)(b * Sk + kt * 64 + kc * 32 + sq * 8)) * F + h * 64 + nt * 16 + sn;
        long outH = blkbase + ((((ri * 2 + 0) * 2 + kc) * 4 + nt) * 64 + sl) * 8;
        long outL = blkbase + ((((ri * 2 + 1) * 2 + kc) * 4 + nt) * 64 + sl) * 8;
#pragma unroll
        for (int j = 0; j < 8; j++) {
            float x = src[base + (long)j * F];
            short xh = f2bf(x);
            pV[outH + j] = xh;
            pV[outL + j] = f2bf(x - bf2f(xh));
        }
    }
}

// ------------------------------- MFMA flash complex attention (bf16x3 exact)
// 64-key tiles; P hi/lo buffer aliases into sK after the 3rd barrier (all score
// reads done; per-wave disjoint slices, wave-local write->read).
__global__ __launch_bounds__(256)
void cattn_mfma(const float* __restrict__ qr, const float* __restrict__ qi,
                const short* __restrict__ pK, const short* __restrict__ pV,
                bf16* __restrict__ dR, bf16* __restrict__ dI,
                int S, int Sk)
{
    __shared__ short sK[16384];   // 32 KB (P alias lives here post-b3)
    __shared__ short sV[16384];   // 32 KB
    const int F = FF;
    int L = blockIdx.x;
    int xcd = L & 7, idx = L >> 3;
    int bh = xcd * 4 + (idx & 3);
    int qt = idx >> 2;
    int b = bh >> 3, h = bh & 7;
    int t = threadIdx.x;
    int w = t >> 6, l = t & 63, q = l >> 4, n16 = l & 15;

    bf16x8 qh_[2][2], ql_[2][2];
    {
        long qbase = ((long)(b * S + qt * 64 + w * 16 + n16)) * F + h * 64 + q * 8;
#pragma unroll
        for (int ri = 0; ri < 2; ri++) {
            const float* src = ri ? qi : qr;
#pragma unroll
            for (int c = 0; c < 2; c++) {
                float vv[8];
                *(float4*)&vv[0] = *(const float4*)&src[qbase + c * 32];
                *(float4*)&vv[4] = *(const float4*)&src[qbase + c * 32 + 4];
#pragma unroll
                for (int j = 0; j < 8; j++) {
                    short xh = f2bf(vv[j]);
                    qh_[ri][c][j] = xh;
                    ql_[ri][c][j] = f2bf(vv[j] - bf2f(xh));
                }
            }
        }
    }

    f32x4 zf = {0.f, 0.f, 0.f, 0.f};
    f32x4 oR[4], oI[4];
#pragma unroll
    for (int nt = 0; nt < 4; nt++) { oR[nt] = zf; oI[nt] = zf; }
    float m_run[4] = {-3.0e38f, -3.0e38f, -3.0e38f, -3.0e38f};
    float l_run[4] = {0.f, 0.f, 0.f, 0.f};

    int nkt = Sk >> 6;
    long pbh = (long)((b * 8 + h) * nkt) * 16384;
    for (int kt = 0; kt < nkt; kt++) {
        __syncthreads();                       // b1: prior PV reads done
        long pb = pbh + (long)kt * 16384;
#pragma unroll
        for (int i = 0; i < 8; i++) {
            int bk = w * 8 + i;
            gload16(pK + pb + (bk << 9) + l * 8, &sK[bk << 9]);
            gload16(pV + pb + (bk << 9) + l * 8, &sV[bk << 9]);
        }
        __syncthreads();                       // b2: staging complete

        // ---- scores over 64 keys (x3)
        f32x4 sc[4];
        sc[0] = zf; sc[1] = zf; sc[2] = zf; sc[3] = zf;
#pragma unroll
        for (int nt = 0; nt < 4; nt++) {
#pragma unroll
            for (int ri = 0; ri < 2; ri++) {
                bf16x8 kh0 = *(const bf16x8*)&sK[((((ri * 2 + 0) * 2 + 0) * 4 + nt) * 64 + l) * 8];
                bf16x8 kh1 = *(const bf16x8*)&sK[((((ri * 2 + 0) * 2 + 1) * 4 + nt) * 64 + l) * 8];
                bf16x8 kl0 = *(const bf16x8*)&sK[((((ri * 2 + 1) * 2 + 0) * 4 + nt) * 64 + l) * 8];
                bf16x8 kl1 = *(const bf16x8*)&sK[((((ri * 2 + 1) * 2 + 1) * 4 + nt) * 64 + l) * 8];
                sc[nt] = __builtin_amdgcn_mfma_f32_16x16x32_bf16(qh_[ri][0], kh0, sc[nt], 0, 0, 0);
                sc[nt] = __builtin_amdgcn_mfma_f32_16x16x32_bf16(qh_[ri][1], kh1, sc[nt], 0, 0, 0);
                sc[nt] = __builtin_amdgcn_mfma_f32_16x16x32_bf16(ql_[ri][0], kh0, sc[nt], 0, 0, 0);
                sc[nt] = __builtin_amdgcn_mfma_f32_16x16x32_bf16(ql_[ri][1], kh1, sc[nt], 0, 0, 0);
                sc[nt] = __builtin_amdgcn_mfma_f32_16x16x32_bf16(qh_[ri][0], kl0, sc[nt], 0, 0, 0);
                sc[nt] = __builtin_amdgcn_mfma_f32_16x16x32_bf16(qh_[ri][1], kl1, sc[nt], 0, 0, 0);
            }
        }
        // ---- online softmax (64 keys per pass)
        float alpha[4];
#pragma unroll
        for (int v = 0; v < 4; v++) {
            float s0 = sc[0][v] * 0.125f, s1 = sc[1][v] * 0.125f;
            float s2 = sc[2][v] * 0.125f, s3 = sc[3][v] * 0.125f;
            float mx = fmaxf(fmaxf(s0, s1), fmaxf(s2, s3));
            mx = fmaxf(mx, __shfl_xor(mx, 1));
            mx = fmaxf(mx, __shfl_xor(mx, 2));
            mx = fmaxf(mx, __shfl_xor(mx, 4));
            mx = fmaxf(mx, __shfl_xor(mx, 8));
            float mnew = fmaxf(m_run[v], mx);
            float p0 = __expf(s0 - mnew), p1 = __expf(s1 - mnew);
            float p2 = __expf(s2 - mnew), p3 = __expf(s3 - mnew);
            sc[0][v] = p0; sc[1][v] = p1; sc[2][v] = p2; sc[3][v] = p3;
            float ps = (p0 + p1) + (p2 + p3);
            ps += __shfl_xor(ps, 1);
            ps += __shfl_xor(ps, 2);
            ps += __shfl_xor(ps, 4);
            ps += __shfl_xor(ps, 8);
            alpha[v] = __expf(m_run[v] - mnew);
            l_run[v] = l_run[v] * alpha[v] + ps;
            m_run[v] = mnew;
        }
#pragma unroll
        for (int nt = 0; nt < 4; nt++)
#pragma unroll
            for (int v = 0; v < 4; v++) { oR[nt][v] *= alpha[v]; oI[nt][v] *= alpha[v]; }
        __syncthreads();                       // b3: score reads of sK done
        // ---- P -> sK alias (per-wave slice): [hl][kc][16][40]
        int pbase = w * 2560;
#pragma unroll
        for (int nt = 0; nt < 4; nt++) {
            int kc = nt >> 1;
            int kk = (nt & 1) * 16 + n16;
#pragma unroll
            for (int v = 0; v < 4; v++) {
                float p = sc[nt][v];
                short ph = f2bf(p);
                short pl = f2bf(p - bf2f(ph));
                int idxp = pbase + kc * 640 + (q * 4 + v) * 40 + kk;
                sK[idxp] = ph;
                sK[idxp + 1280] = pl;
            }
        }
        bf16x8 pH[2], pL[2];
#pragma unroll
        for (int kc = 0; kc < 2; kc++) {
            pH[kc] = *(const bf16x8*)&sK[pbase + kc * 640 + n16 * 40 + q * 8];
            pL[kc] = *(const bf16x8*)&sK[pbase + 1280 + kc * 640 + n16 * 40 + q * 8];
        }
        // ---- PV (x3)
#pragma unroll
        for (int nt = 0; nt < 4; nt++) {
#pragma unroll
            for (int kc = 0; kc < 2; kc++) {
                bf16x8 vh  = *(const bf16x8*)&sV[((((0 * 2 + 0) * 2 + kc) * 4 + nt) * 64 + l) * 8];
                bf16x8 vl  = *(const bf16x8*)&sV[((((0 * 2 + 1) * 2 + kc) * 4 + nt) * 64 + l) * 8];
                oR[nt] = __builtin_amdgcn_mfma_f32_16x16x32_bf16(pH[kc], vh, oR[nt], 0, 0, 0);
                oR[nt] = __builtin_amdgcn_mfma_f32_16x16x32_bf16(pL[kc], vh, oR[nt], 0, 0, 0);
                oR[nt] = __builtin_amdgcn_mfma_f32_16x16x32_bf16(pH[kc], vl, oR[nt], 0, 0, 0);
                bf16x8 wh  = *(const bf16x8*)&sV[((((1 * 2 + 0) * 2 + kc) * 4 + nt) * 64 + l) * 8];
                bf16x8 wl2 = *(const bf16x8*)&sV[((((1 * 2 + 1) * 2 + kc) * 4 + nt) * 64 + l) * 8];
                oI[nt] = __builtin_amdgcn_mfma_f32_16x16x32_bf16(pH[kc], wh, oI[nt], 0, 0, 0);
                oI[nt] = __builtin_amdgcn_mfma_f32_16x16x32_bf16(pL[kc], wh, oI[nt], 0, 0, 0);
                oI[nt] = __builtin_amdgcn_mfma_f32_16x16x32_bf16(pH[kc], wl2, oI[nt], 0, 0, 0);
            }
        }
    }
    // ---- epilogue: write [Ah|Al] expanded rows of A1 directly
#pragma unroll
    for (int v = 0; v < 4; v++) {
        float inv = 1.0f / l_run[v];
        long rbase = ((long)(b * S + qt * 64 + w * 16 + q * 4 + v)) * 1024;
#pragma unroll
        for (int nt = 0; nt < 4; nt++) {
            int col = h * 64 + nt * 16 + n16;
            float vr = oR[nt][v] * inv;
            bf16 hh = __float2bfloat16(vr);
            dR[rbase + col] = hh;
            dR[rbase + 512 + col] = __float2bfloat16(vr - __bfloat162float(hh));
            float vi = oI[nt][v] * inv;
            bf16 hi2 = __float2bfloat16(vi);
            dI[rbase + col] = hi2;
            dI[rbase + 512 + col] = __float2bfloat16(vi - __bfloat162float(hi2));
        }
    }
}

// ---------------------------------------------------- MoE routing tables
__global__ __launch_bounds__(256)
void moe_build_kernel(const int* __restrict__ eidx, int* __restrict__ order,
                      int* __restrict__ te128, int* __restrict__ te64)
{
    __shared__ int cnt[NEXP], segbase[NEXP], cursor[NEXP], tb128[NEXP], n128[NEXP];
    int t = threadIdx.x;
    if (t < NEXP) { cnt[t] = 0; cursor[t] = 0; }
    __syncthreads();
    for (int i = t; i < NTOK; i += 256) atomicAdd(&cnt[eidx[i]], 1);
    __syncthreads();
    if (t == 0) {
        int ob = 0, tb = 0;
        for (int e = 0; e < NEXP; e++) {
            segbase[e] = ob; tb128[e] = tb;
            int tiles = (cnt[e] + 127) >> 7;
            n128[e] = tiles;
            ob += tiles << 7; tb += tiles;
        }
    }
    __syncthreads();
    for (int i = t; i < NPAD128; i += 256) order[i] = -1;
    if (t < TMAX128) {
        int ex = -1;
        for (int e = 0; e < NEXP; e++)
            if (t >= tb128[e] && t < tb128[e] + n128[e]) ex = e;
        te128[t] = ex;
    }
    if (t >= 64 && t < 64 + 2 * TMAX128) {
        int tt = t - 64;
        int ex = -1;
        for (int e = 0; e < NEXP; e++)
            if (tt >= tb128[e] * 2 && tt < (tb128[e] + n128[e]) * 2) ex = e;
        te64[tt] = ex;
    }
    __syncthreads();
    for (int i = t; i < NTOK; i += 256) {
        int e = eidx[i];
        int pos = atomicAdd(&cursor[e], 1);
        order[segbase[e] + pos] = i;
    }
}

__global__ __launch_bounds__(256)
void combine_kernel(const int* __restrict__ order,
                    const float* __restrict__ xr, const float* __restrict__ xi,
                    const float* __restrict__ yr, const float* __restrict__ yi,
                    float* __restrict__ out)
{
    const int F = FF;
    int p = blockIdx.x;
    int tok = order[p];
    if (tok < 0) return;
    int t = threadIdx.x;
    float* outr = out;
    float* outi = out + (long)NTOK * FF;
#pragma unroll
    for (int u = 0; u < 2; u++) {
        int j = t + u * 256;
        long src = (long)p * F + j;
        long dst = (long)tok * F + j;
        outr[dst] = xr[dst] + yr[src];
        outi[dst] = xi[dst] + yi[src];
    }
}

// ------------------------------------------------------------------- launch
extern "C" void kernel_launch(void* const* d_in, const int* in_sizes, int n_in,
                              void* d_out, int out_size, void* d_ws, size_t ws_size,
                              hipStream_t stream)
{
    (void)in_sizes; (void)n_in; (void)out_size; (void)ws_size;
    const float* x_r   = (const float*)d_in[0];
    const float* x_i   = (const float*)d_in[1];
    const float* ctx_r = (const float*)d_in[2];
    const float* ctx_i = (const float*)d_in[3];
    const float* ln1_g = (const float*)d_in[4];
    const float* ln2_g = (const float*)d_in[5];
    const float* ln3_g = (const float*)d_in[6];
    const float* sa_qWr = (const float*)d_in[7];   const float* sa_qWi = (const float*)d_in[8];
    const float* sa_qbr = (const float*)d_in[9];   const float* sa_qbi = (const float*)d_in[10];
    const float* sa_kWr = (const float*)d_in[11];  const float* sa_kWi = (const float*)d_in[12];
    const float* sa_kbr = (const float*)d_in[13];  const float* sa_kbi = (const float*)d_in[14];
    const float* sa_vWr = (const float*)d_in[15];  const float* sa_vWi = (const float*)d_in[16];
    const float* sa_vbr = (const float*)d_in[17];  const float* sa_vbi = (const float*)d_in[18];
    const float* sa_oWr = (const float*)d_in[19];  const float* sa_oWi = (const float*)d_in[20];
    const float* sa_obr = (const float*)d_in[21];  const float* sa_obi = (const float*)d_in[22];
    const float* ca_qWr = (const float*)d_in[23];  const float* ca_qWi = (const float*)d_in[24];
    const float* ca_qbr = (const float*)d_in[25];  const float* ca_qbi = (const float*)d_in[26];
    const float* ca_kWr = (const float*)d_in[27];  const float* ca_kWi = (const float*)d_in[28];
    const float* ca_kbr = (const float*)d_in[29];  const float* ca_kbi = (const float*)d_in[30];
    const float* ca_vWr = (const float*)d_in[31];  const float* ca_vWi = (const float*)d_in[32];
    const float* ca_vbr = (const float*)d_in[33];  const float* ca_vbi = (const float*)d_in[34];
    const float* ca_oWr = (const float*)d_in[35];  const float* ca_oWi = (const float*)d_in[36];
    const float* ca_obr = (const float*)d_in[37];  const float* ca_obi = (const float*)d_in[38];
    const float* moe_W1r = (const float*)d_in[39]; const float* moe_W1i = (const float*)d_in[40];
    const float* moe_b1r = (const float*)d_in[41]; const float* moe_b1i = (const float*)d_in[42];
    const float* moe_mb  = (const float*)d_in[43];
    const float* moe_W2r = (const float*)d_in[44]; const float* moe_W2i = (const float*)d_in[45];
    const float* moe_b2r = (const float*)d_in[46]; const float* moe_b2i = (const float*)d_in[47];
    float* out = (float*)d_out;

    char* W = (char*)d_ws;
    const long NF = (long)NTOK * FF;
    const long NF4 = NF * 4;                      // 8 MB
    float* xr = (float*)(W + 0 * NF4);
    float* xi = (float*)(W + 1 * NF4);
    char* base2 = W + 2 * NF4;                    // 16.8 MB region
    short* pKbuf = (short*)base2;                 // attention phase
    bf16* h3r = (bf16*)base2;                     // MoE phase
    bf16* h3i = (bf16*)(base2 + 4194304);
    char* poolB = W + 4 * NF4;                    // 67.1 MB pool
    float* qr = (float*)poolB;                float* qi = (float*)(poolB + NF4);
    float* kr = (float*)(poolB + 2 * NF4);    float* ki = (float*)(poolB + 3 * NF4);
    float* vr = (float*)(poolB + 4 * NF4);    float* vi = (float*)(poolB + 5 * NF4);
    short* pVbuf = (short*)(poolB + 6 * NF4);     // attention phase (16.8 MB)
    bf16* u_r = (bf16*)poolB;                     // MoE overlay: 5120x2048
    bf16* u_i = (bf16*)(poolB + 20971520);
    float* y_r = (float*)(poolB + 41943040);      // 5120x512 f32
    float* y_i = (float*)(poolB + 52428800);
    char* Q = W + 12 * NF4;
    bf16* A1r = (bf16*)Q;                         // 4096x1024
    bf16* A1i = (bf16*)(Q + 8388608);
    bf16* A2r = (bf16*)(Q + 16777216);            // 1024x1536
    bf16* A2i = (bf16*)(Q + 19922944);
    char* WQ = Q + 23068672;
    const long PS1 = 524288;
    const long PS2 = 786432;
    bf16* saq_r = (bf16*)(WQ);                   bf16* saq_i = saq_r + PS1;
    bf16* sak_r = saq_r + 2 * PS1;               bf16* sak_i = saq_r + 3 * PS1;
    bf16* sav_r = saq_r + 4 * PS1;               bf16* sav_i = saq_r + 5 * PS1;
    bf16* sao_r = saq_r + 6 * PS1;               bf16* sao_i = saq_r + 7 * PS1;
    bf16* caq_r = saq_r + 8 * PS1;               bf16* caq_i = saq_r + 9 * PS1;
    bf16* cao_r = saq_r + 10 * PS1;              bf16* cao_i = saq_r + 11 * PS1;
    bf16* cak_r = saq_r + 12 * PS1;              bf16* cak_i = cak_r + PS2;
    bf16* cav_r = cak_r + 2 * PS2;               bf16* cav_i = cak_r + 3 * PS2;
    bf16* Wm_r = (bf16*)Q;                        // MoE weight overlay
    bf16* Wm_i = (bf16*)(Q + 16777216);
    char* ints = W + 12 * NF4 + 41943040 + 524288;   // past WQ end, padded
    int* eidx  = (int*)ints;
    int* order = eidx + NTOK;
    int* te128 = order + NPAD128;
    int* te64  = te128 + 64;

    dim3 blk(256);
    const long W1S = (long)FF * HID;
    const long CZ = 2 * NF4;
    Ptr6 bQKV = {{sa_qbr, sa_qbi, sa_kbr, sa_kbi, sa_vbr, sa_vbi}};
    Ptr6 bSAO = {{sa_obr, sa_obi, 0, 0, 0, 0}};
    Ptr6 bCAQ = {{ca_qbr, ca_qbi, 0, 0, 0, 0}};
    Ptr6 bCKV = {{ca_kbr, ca_kbi, ca_vbr, ca_vbi, 0, 0}};
    Ptr6 bCAO = {{ca_obr, ca_obi, 0, 0, 0, 0}};
    Ptr6 bM1  = {{moe_b1r, moe_b1i, 0, 0, 0, 0}};
    Ptr6 bM2  = {{moe_b2r, moe_b2i, 0, 0, 0, 0}};

    // ---- all 8 attention weight packs in one dispatch
    WPackAll wp;
    wp.sR[0]=sa_qWr; wp.sI[0]=sa_qWi; wp.dR[0]=saq_r; wp.dI[0]=saq_i; wp.kdiv[0]=16;
    wp.sR[1]=sa_kWr; wp.sI[1]=sa_kWi; wp.dR[1]=sak_r; wp.dI[1]=sak_i; wp.kdiv[1]=16;
    wp.sR[2]=sa_vWr; wp.sI[2]=sa_vWi; wp.dR[2]=sav_r; wp.dI[2]=sav_i; wp.kdiv[2]=16;
    wp.sR[3]=sa_oWr; wp.sI[3]=sa_oWi; wp.dR[3]=sao_r; wp.dI[3]=sao_i; wp.kdiv[3]=16;
    wp.sR[4]=ca_qWr; wp.sI[4]=ca_qWi; wp.dR[4]=caq_r; wp.dI[4]=caq_i; wp.kdiv[4]=16;
    wp.sR[5]=ca_oWr; wp.sI[5]=ca_oWi; wp.dR[5]=cao_r; wp.dI[5]=cao_i; wp.kdiv[5]=16;
    wp.sR[6]=ca_kWr; wp.sI[6]=ca_kWi; wp.dR[6]=cak_r; wp.dI[6]=cak_i; wp.kdiv[6]=24;
    wp.sR[7]=ca_vWr; wp.sI[7]=ca_vWi; wp.dR[7]=cav_r; wp.dI[7]=cav_i; wp.kdiv[7]=24;
    expandW_all<<<dim3(8, 48, 8), blk, 0, stream>>>(wp);

    // ---- self-attention block
    cln_expand<<<NTOK, blk, 0, stream>>>(x_r, x_i, ln1_g, A1r, A1i);
    cgemm128<true,false,false,false,false,false><<<dim3(32, 4, 3), blk, 0, stream>>>(
        A1r, A1i, 1024, 512, saq_r, saq_i, 2 * PS1, 0, 32, 16,
        bQKV, 0, nullptr, nullptr, nullptr, qr, qi, CZ, FF, 1536, 0, nullptr, nullptr);
    pack_kv<<<dim3(16, 8, 4), blk, 0, stream>>>(kr, ki, vr, vi, pKbuf, pVbuf, 1024);
    cattn_mfma<<<512, blk, 0, stream>>>(qr, qi, pKbuf, pVbuf, A1r, A1i, 1024, 1024);
    cgemm128<true,false,false,false,true,false><<<128, blk, 0, stream>>>(
        A1r, A1i, 1024, 512, sao_r, sao_i, 0, 0, 32, 16,
        bSAO, 0, nullptr, x_r, x_i, xr, xi, 0, FF, 1536, 4, nullptr, nullptr);

    // ---- cross-attention block
    cln_expand<<<NTOK, blk, 0, stream>>>(xr, xi, ln2_g, A1r, A1i);
    cgemm128<true,false,false,false,false,false><<<128, blk, 0, stream>>>(
        A1r, A1i, 1024, 512, caq_r, caq_i, 0, 0, 32, 16,
        bCAQ, 0, nullptr, nullptr, nullptr, qr, qi, 0, FF, 1536, 4, nullptr, nullptr);
    expandA_x2<<<dim3(3, 1024), blk, 0, stream>>>(ctx_r, ctx_i, A2r, A2i, CDIM);
    cgemm_mfma<true,false,false,false,false,false><<<dim3(16, 8, 2), blk, 0, stream>>>(
        A2r, A2i, 1536, 768, cak_r, cak_i, 2 * PS2, 0, 32, 24,
        bCKV, 0, nullptr, nullptr, nullptr, kr, ki, CZ, FF, 2304, nullptr, nullptr);
    pack_kv<<<dim3(4, 8, 4), blk, 0, stream>>>(kr, ki, vr, vi, pKbuf, pVbuf, 256);
    cattn_mfma<<<512, blk, 0, stream>>>(qr, qi, pKbuf, pVbuf, A1r, A1i, 1024, 256);
    cgemm128<true,false,false,false,true,false><<<128, blk, 0, stream>>>(
        A1r, A1i, 1024, 512, cao_r, cao_i, 0, 0, 32, 16,
        bCAO, 0, nullptr, xr, xi, xr, xi, 0, FF, 1536, 4, nullptr, nullptr);

    // ---- phase-routed MoE
    cln_route<<<NTOK, blk, 0, stream>>>(xr, xi, ln3_g, h3r, h3i, eidx);
    moe_build_kernel<<<1, blk, 0, stream>>>(eidx, order, te128, te64);
    convW_packed<<<dim3(32, 16, 8), blk, 0, stream>>>(moe_W1r, moe_W1i, Wm_r, Wm_i, HID, W1S);
    cgemm128<false,true,true,true,false,true><<<640, blk, 0, stream>>>(
        h3r, h3i, 512, 512, Wm_r, Wm_i, 0, W1S, 128, 0,
        bM1, HID, moe_mb, nullptr, nullptr, u_r, u_i, 0, HID, 512, 5, order, te128);
    convW_packed<<<dim3(8, 64, 8), blk, 0, stream>>>(moe_W2r, moe_W2i, Wm_r, Wm_i, FF, W1S);
    cgemm128<false,true,false,false,false,false><<<160, blk, 0, stream>>>(
        u_r, u_i, 2048, 2048, Wm_r, Wm_i, 0, W1S, 32, 0,
        bM2, FF, nullptr, nullptr, nullptr, y_r, y_i, 0, FF, 2048, 5, nullptr, te128);
    combine_kernel<<<NPAD128, blk, 0, stream>>>(order, xr, xi, y_r, y_i, out);
}